// Round 14
// baseline (198.902 us; speedup 1.0000x reference)
//
#include <hip/hip_runtime.h>
#include <cstdio>

#define HID 64
#define D 128            // 2*HID
#define NUM_REL 230
#define NUM_TS 365
#define NCOMB (NUM_REL*NUM_TS)   // 83950
#define SLOPE 0.2f
#define XPAD 136         // LDS row stride in bf16 (272 B -> bank stride 4, 2-way = free)
#define MAXDEG 64        // Poisson(8) max degree ~25; P(deg>=64) < 1e-40

typedef __attribute__((ext_vector_type(8))) short short8;
typedef __attribute__((ext_vector_type(4))) float f32x4;

__device__ __forceinline__ float lrelu(float v){ return v >= 0.f ? v : SLOPE*v; }

// bf16 helpers
__device__ __forceinline__ unsigned bf_rne(float f){
    unsigned u = __float_as_uint(f);
    return (u + 0x7fffu + ((u >> 16) & 1u)) >> 16;
}
__device__ __forceinline__ unsigned pk2(float a, float b){
    return bf_rne(a) | (bf_rne(b) << 16);
}
__device__ __forceinline__ float bf_lo(unsigned u){ return __uint_as_float(u << 16); }
__device__ __forceinline__ float bf_hi(unsigned u){ return __uint_as_float(u & 0xffff0000u); }

// pack 8 fp32 (two float4) -> short8 bf16 frag, memory order preserved
__device__ __forceinline__ short8 pack8(float4 a, float4 b){
    short8 r;
    r[0]=(short)bf_rne(a.x); r[1]=(short)bf_rne(a.y);
    r[2]=(short)bf_rne(a.z); r[3]=(short)bf_rne(a.w);
    r[4]=(short)bf_rne(b.x); r[5]=(short)bf_rne(b.y);
    r[6]=(short)bf_rne(b.z); r[7]=(short)bf_rne(b.w);
    return r;
}
__device__ __forceinline__ float4 lr4(float4 a, float4 b, float4 c){
    return make_float4(lrelu(a.x+b.x+c.x), lrelu(a.y+b.y+c.y),
                       lrelu(a.z+b.z+c.z), lrelu(a.w+b.w+c.w));
}

// ---------------------------------------------------------------------------
// k_prep: parts (relP/timP) + W-pack ONLY.  (round-5 form, ~12 µs)
// ---------------------------------------------------------------------------
__global__ __launch_bounds__(256) void k_prep(
        const float* __restrict__ rel_table, const float* __restrict__ time_table,
        const float* __restrict__ W_rt, const float* __restrict__ W_fc,
        float* __restrict__ relP, float* __restrict__ timP,
        unsigned short* __restrict__ Wpk13, unsigned short* __restrict__ Wpk2)
{
    int b = blockIdx.x;
    if (b < 298) {
        int row = b*2 + (threadIdx.x >> 7);
        int j   = threadIdx.x & 127;
        if (row >= NUM_REL + NUM_TS) return;
        const float* tbl; const float* Wb; float* out;
        if (row < NUM_REL) { tbl = rel_table + row*HID;            Wb = W_rt;          out = relP + row*D; }
        else               { tbl = time_table + (row-NUM_REL)*HID; Wb = W_rt + HID*D;  out = timP + (row-NUM_REL)*D; }
        float acc = 0.f;
        #pragma unroll
        for (int k = 0; k < HID; ++k) acc += tbl[k] * Wb[k*D + j];
        out[j] = acc;
    } else {
        int id = (b - 298)*256 + threadIdx.x;   // 0..6143
        if (id < 4096) {                 // W13 frags
            int mt = id >> 8;            // 0..15
            int s  = (id >> 6) & 3;
            int l  = id & 63;
            int m  = mt*16 + (l & 15);   // output col 0..255
            int kb = s*32 + (l >> 4)*8;
            unsigned short* dst = Wpk13 + ((size_t)(mt*4 + s)*64 + l)*8;
            #pragma unroll
            for (int j = 0; j < 8; ++j) {
                int k = kb + j;
                float v = (m < D) ? W_fc[(size_t)k*D + m]
                                  : W_fc[(size_t)(256 + k)*D + (m - D)];
                dst[j] = (unsigned short)bf_rne(v);
            }
        } else {                         // W2 frags
            int id2 = id - 4096;
            int mt = id2 >> 8;           // 0..7
            int s  = (id2 >> 6) & 3;
            int l  = id2 & 63;
            int m  = mt*16 + (l & 15);
            int kb = s*32 + (l >> 4)*8;
            unsigned short* dst = Wpk2 + ((size_t)(mt*4 + s)*64 + l)*8;
            #pragma unroll
            for (int j = 0; j < 8; ++j) {
                int k = kb + j;
                dst[j] = (unsigned short)bf_rne(W_fc[(size_t)(D + k)*D + m]);
            }
        }
    }
}

// ---------------------------------------------------------------------------
// k_mm — BARRIER-FREE mm bodies (round-13 design, resubmitted after broker
// failure; never measured).
// r12 diagnosis: ~21K cycles/wave vs ~2K of issue, every pipe <25% busy,
// duration insensitive to occupancy (r7/r9) and to LDS conflicts (r12) —
// consistent with barrier-convoy phasing: stage->sync->MFMA->sync couples
// all waves of lockstep-dispatched blocks to the same phase.
// Fix: B-fragments are 8 contiguous row elements -> load DIRECTLY from
// global (2x float4, 64B-line coalesced per 16-lane row group) and convert
// in-register. Xs/Hs and both pre-MFMA __syncthreads deleted; blocks are
// pure dataflow until the Cs epilogue (r11/12's proven coalesced store).
// Cost: 4x L2 re-read of x/relP/timP (~9 µs chip-wide at 34.5 TB/s, hidden)
// + redundant per-wave lrelu VALU in t2 (~1.6K cy/wave, cheap vs 19K stall).
// ---------------------------------------------------------------------------
__device__ __forceinline__ void xw_body(
        int xb, const float* __restrict__ x,
        const unsigned short* __restrict__ Wpk13,
        unsigned short* __restrict__ xW13bf, int n_nodes,
        unsigned short* Cs /* 64*XPAD */)
{
    int t = threadIdx.x;
    int w = t >> 6, l = t & 63;
    int li = l & 15, q = l >> 4;
    int nodeBase = xb*64;

    // lane-fixed B-row pointers (clamped in-bounds; clamped rows only feed
    // acc columns for node>=n_nodes, which the store skips)
    const float* xr0 = x + (size_t)min(nodeBase +  0 + li, n_nodes-1)*D + q*8;
    const float* xr1 = x + (size_t)min(nodeBase + 16 + li, n_nodes-1)*D + q*8;
    const float* xr2 = x + (size_t)min(nodeBase + 32 + li, n_nodes-1)*D + q*8;
    const float* xr3 = x + (size_t)min(nodeBase + 48 + li, n_nodes-1)*D + q*8;

    #pragma unroll 1            // halves sequential (acc reuse, reg economy)
    for (int h = 0; h < 2; ++h) {
        f32x4 acc[2][4];
        #pragma unroll
        for (int mi = 0; mi < 2; ++mi)
            #pragma unroll
            for (int ni = 0; ni < 4; ++ni) acc[mi][ni] = (f32x4){0.f,0.f,0.f,0.f};

        #pragma unroll 1
        for (int s = 0; s < 4; ++s) {
            short8 af0 = *(const short8*)(Wpk13 + ((size_t)((w*4 + h*2 + 0)*4 + s)*64 + l)*8);
            short8 af1 = *(const short8*)(Wpk13 + ((size_t)((w*4 + h*2 + 1)*4 + s)*64 + l)*8);
            float4 a0 = *(const float4*)(xr0 + s*32), b0 = *(const float4*)(xr0 + s*32 + 4);
            float4 a1 = *(const float4*)(xr1 + s*32), b1 = *(const float4*)(xr1 + s*32 + 4);
            float4 a2 = *(const float4*)(xr2 + s*32), b2 = *(const float4*)(xr2 + s*32 + 4);
            float4 a3 = *(const float4*)(xr3 + s*32), b3 = *(const float4*)(xr3 + s*32 + 4);
            short8 bf0 = pack8(a0, b0);
            short8 bf1 = pack8(a1, b1);
            short8 bf2 = pack8(a2, b2);
            short8 bf3 = pack8(a3, b3);
            acc[0][0] = __builtin_amdgcn_mfma_f32_16x16x32_bf16(af0, bf0, acc[0][0], 0, 0, 0);
            acc[0][1] = __builtin_amdgcn_mfma_f32_16x16x32_bf16(af0, bf1, acc[0][1], 0, 0, 0);
            acc[0][2] = __builtin_amdgcn_mfma_f32_16x16x32_bf16(af0, bf2, acc[0][2], 0, 0, 0);
            acc[0][3] = __builtin_amdgcn_mfma_f32_16x16x32_bf16(af0, bf3, acc[0][3], 0, 0, 0);
            acc[1][0] = __builtin_amdgcn_mfma_f32_16x16x32_bf16(af1, bf0, acc[1][0], 0, 0, 0);
            acc[1][1] = __builtin_amdgcn_mfma_f32_16x16x32_bf16(af1, bf1, acc[1][1], 0, 0, 0);
            acc[1][2] = __builtin_amdgcn_mfma_f32_16x16x32_bf16(af1, bf2, acc[1][2], 0, 0, 0);
            acc[1][3] = __builtin_amdgcn_mfma_f32_16x16x32_bf16(af1, bf3, acc[1][3], 0, 0, 0);
        }
        // acc -> Cs (padded stride: 2-way banks, free)
        #pragma unroll
        for (int ni = 0; ni < 4; ++ni)
            #pragma unroll
            for (int mi = 0; mi < 2; ++mi) {
                int node = ni*16 + li;
                int cl   = w*32 + mi*16 + q*4;
                *(uint2*)(Cs + node*XPAD + cl) =
                    make_uint2(pk2(acc[mi][ni][0], acc[mi][ni][1]),
                               pk2(acc[mi][ni][2], acc[mi][ni][3]));
            }
        __syncthreads();
        // coalesced store: per instr, 64 lanes x 16B lane-contiguous = 1KB.
        // global col = (off>>6)*128 + h*64 + (off&63)  (off in bytes)
        #pragma unroll
        for (int k = 0; k < 4; ++k) {
            int flat  = (k*4 + w)*1024 + l*16;
            int nodeL = flat >> 8;
            int off   = flat & 255;
            int node  = nodeBase + nodeL;
            if (node < n_nodes) {
                uint4 v = *(const uint4*)((const char*)Cs + nodeL*(XPAD*2) + off);
                *(uint4*)((char*)(xW13bf + (size_t)node*256)
                          + (off >> 6)*128 + h*64 + (off & 63)) = v;
            }
        }
        __syncthreads();   // Cs reads done before next half rewrites it
    }
}

__device__ __forceinline__ void t2_body(
        int tb, const float* __restrict__ relP, const float* __restrict__ timP,
        const float* __restrict__ b_rt, const unsigned short* __restrict__ Wpk2,
        unsigned short* __restrict__ T2bf,
        unsigned short* Cs /* 64*XPAD */)
{
    int t = threadIdx.x;
    int w = t >> 6, l = t & 63;
    int li = l & 15, q = l >> 4;
    int cBase = tb*64;

    // lane-fixed combo rows (clamped; clamped columns skipped at store)
    int c0 = min(cBase +  0 + li, NCOMB-1);
    int c1 = min(cBase + 16 + li, NCOMB-1);
    int c2 = min(cBase + 32 + li, NCOMB-1);
    int c3 = min(cBase + 48 + li, NCOMB-1);
    int rr0 = c0 / NUM_TS, tt0 = c0 - rr0*NUM_TS;
    int rr1 = c1 / NUM_TS, tt1 = c1 - rr1*NUM_TS;
    int rr2 = c2 / NUM_TS, tt2 = c2 - rr2*NUM_TS;
    int rr3 = c3 / NUM_TS, tt3 = c3 - rr3*NUM_TS;
    const float* rp0 = relP + (size_t)rr0*D + q*8;
    const float* rp1 = relP + (size_t)rr1*D + q*8;
    const float* rp2 = relP + (size_t)rr2*D + q*8;
    const float* rp3 = relP + (size_t)rr3*D + q*8;
    const float* tp0 = timP + (size_t)tt0*D + q*8;
    const float* tp1 = timP + (size_t)tt1*D + q*8;
    const float* tp2 = timP + (size_t)tt2*D + q*8;
    const float* tp3 = timP + (size_t)tt3*D + q*8;

    f32x4 acc[2][4];
    #pragma unroll
    for (int mi = 0; mi < 2; ++mi)
        #pragma unroll
        for (int ni = 0; ni < 4; ++ni) acc[mi][ni] = (f32x4){0.f,0.f,0.f,0.f};

    #pragma unroll 1
    for (int s = 0; s < 4; ++s) {
        short8 af0 = *(const short8*)(Wpk2 + ((size_t)((w*2 + 0)*4 + s)*64 + l)*8);
        short8 af1 = *(const short8*)(Wpk2 + ((size_t)((w*2 + 1)*4 + s)*64 + l)*8);
        float4 ba = *(const float4*)(b_rt + s*32 + q*8);
        float4 bb = *(const float4*)(b_rt + s*32 + q*8 + 4);
        float4 ra0 = *(const float4*)(rp0 + s*32), rb0 = *(const float4*)(rp0 + s*32 + 4);
        float4 ta0 = *(const float4*)(tp0 + s*32), tb0 = *(const float4*)(tp0 + s*32 + 4);
        float4 ra1 = *(const float4*)(rp1 + s*32), rb1 = *(const float4*)(rp1 + s*32 + 4);
        float4 ta1 = *(const float4*)(tp1 + s*32), tb1 = *(const float4*)(tp1 + s*32 + 4);
        float4 ra2 = *(const float4*)(rp2 + s*32), rb2 = *(const float4*)(rp2 + s*32 + 4);
        float4 ta2 = *(const float4*)(tp2 + s*32), tb2 = *(const float4*)(tp2 + s*32 + 4);
        float4 ra3 = *(const float4*)(rp3 + s*32), rb3 = *(const float4*)(rp3 + s*32 + 4);
        float4 ta3 = *(const float4*)(tp3 + s*32), tb3 = *(const float4*)(tp3 + s*32 + 4);
        short8 bf0 = pack8(lr4(ra0, ta0, ba), lr4(rb0, tb0, bb));
        short8 bf1 = pack8(lr4(ra1, ta1, ba), lr4(rb1, tb1, bb));
        short8 bf2 = pack8(lr4(ra2, ta2, ba), lr4(rb2, tb2, bb));
        short8 bf3 = pack8(lr4(ra3, ta3, ba), lr4(rb3, tb3, bb));
        acc[0][0] = __builtin_amdgcn_mfma_f32_16x16x32_bf16(af0, bf0, acc[0][0], 0, 0, 0);
        acc[0][1] = __builtin_amdgcn_mfma_f32_16x16x32_bf16(af0, bf1, acc[0][1], 0, 0, 0);
        acc[0][2] = __builtin_amdgcn_mfma_f32_16x16x32_bf16(af0, bf2, acc[0][2], 0, 0, 0);
        acc[0][3] = __builtin_amdgcn_mfma_f32_16x16x32_bf16(af0, bf3, acc[0][3], 0, 0, 0);
        acc[1][0] = __builtin_amdgcn_mfma_f32_16x16x32_bf16(af1, bf0, acc[1][0], 0, 0, 0);
        acc[1][1] = __builtin_amdgcn_mfma_f32_16x16x32_bf16(af1, bf1, acc[1][1], 0, 0, 0);
        acc[1][2] = __builtin_amdgcn_mfma_f32_16x16x32_bf16(af1, bf2, acc[1][2], 0, 0, 0);
        acc[1][3] = __builtin_amdgcn_mfma_f32_16x16x32_bf16(af1, bf3, acc[1][3], 0, 0, 0);
    }
    // acc -> Cs (padded stride: 2-way banks, free)
    #pragma unroll
    for (int ni = 0; ni < 4; ++ni)
        #pragma unroll
        for (int mi = 0; mi < 2; ++mi) {
            int comboL = ni*16 + li;
            int cl     = (w*2 + mi)*16 + q*4;
            *(uint2*)(Cs + comboL*XPAD + cl) =
                make_uint2(pk2(acc[mi][ni][0], acc[mi][ni][1]),
                           pk2(acc[mi][ni][2], acc[mi][ni][3]));
        }
    __syncthreads();
    // coalesced store: T2bf rows are 256B contiguous -> perfect 1KB/instr
    #pragma unroll
    for (int k = 0; k < 4; ++k) {
        int flat = (k*4 + w)*1024 + l*16;
        int cL   = flat >> 8;
        int off  = flat & 255;
        int combo = cBase + cL;
        if (combo < NCOMB) {
            uint4 v = *(const uint4*)((const char*)Cs + cL*(XPAD*2) + off);
            *(uint4*)((char*)(T2bf + (size_t)combo*D) + off) = v;
        }
    }
}

__global__ __launch_bounds__(256, 3) void k_mm(
        const float* __restrict__ x, const unsigned short* __restrict__ Wpk13,
        unsigned short* __restrict__ xW13bf, int n_nodes,
        const float* __restrict__ relP, const float* __restrict__ timP,
        const float* __restrict__ b_rt, const unsigned short* __restrict__ Wpk2,
        unsigned short* __restrict__ T2bf,
        const int* __restrict__ edges, int n_edges,
        int* __restrict__ deg, int2* __restrict__ ebuf,
        int nsc, int nxw, int ntot)
{
    __shared__ __align__(16) unsigned short Cs[64*XPAD];  // 17.4 KB (only LDS)
    int b = blockIdx.x;
    // Bresenham interleave: scatter block iff cumulative count increments.
    int cumCur  = (int)(((long long)b       * nsc) / ntot);
    int cumNext = (int)(((long long)(b + 1) * nsc) / ntot);
    if (cumNext > cumCur) {
        // edge bucket-scatter (hides under co-resident MFMA blocks:
        // +12 µs vs +30 standalone). deg zeroed by hipMemsetAsync blit
        // (round-3 lesson: plain-store zeroing -> stale atomics).
        int e = cumCur*256 + threadIdx.x;
        if (e < n_edges) {
            int4 ed = ((const int4*)edges)[e];
            int slot = atomicAdd(&deg[ed.y], 1);
            if (slot < MAXDEG)   // safety clamp; statistically never taken
                ebuf[(size_t)ed.y*MAXDEG + slot] = make_int2(ed.x, ed.z*NUM_TS + ed.w);
        }
    } else {
        int cidx = b - cumNext;
        if (cidx < nxw) {
            xw_body(cidx, x, Wpk13, xW13bf, n_nodes, Cs);
        } else {
            t2_body(cidx - nxw, relP, timP, b_rt, Wpk2, T2bf, Cs);
        }
    }
}

// ---------------------------------------------------------------------------
// k_agg: 4 nodes per wave, 16 lanes per node, uint4 (16B) gathers.
// (unchanged — at the random-gather floor for this access pattern)
// ---------------------------------------------------------------------------
__global__ __launch_bounds__(256) void k_agg(
        const int* __restrict__ deg, const int2* __restrict__ ebuf,
        const unsigned short* __restrict__ xW13bf,
        const unsigned short* __restrict__ T2bf,
        const float* __restrict__ b_fc,
        float* __restrict__ out, int n_nodes)
{
    int t    = threadIdx.x;
    int lane = t & 63;
    int g    = lane >> 4;             // node group within wave (0..3)
    int sub  = lane & 15;             // lane within group; covers cols sub*8..+7
    int node = blockIdx.x*16 + (t >> 6)*4 + g;
    bool valid = node < n_nodes;
    int nodeC  = valid ? node : n_nodes - 1;

    int dg  = deg[nodeC];
    int cnt = valid ? (dg < MAXDEG ? dg : MAXDEG) : 0;
    int cm1 = cnt > 0 ? cnt - 1 : 0;
    const int2* eb = ebuf + (size_t)nodeC * MAXDEG;

    // wave-max trip count (cnt is uniform within each 16-lane group)
    int cmax = cnt;
    cmax = max(cmax, __shfl_xor(cmax, 16));
    cmax = max(cmax, __shfl_xor(cmax, 32));

    // base = xW3[node] + b_fc for this lane's 8 cols
    float base[8];
    {
        uint4  w3  = *(const uint4*)&xW13bf[(size_t)nodeC*256 + 128 + sub*8];
        float4 blo = *(const float4*)&b_fc[sub*8];
        float4 bhi = *(const float4*)&b_fc[sub*8 + 4];
        base[0] = bf_lo(w3.x) + blo.x; base[1] = bf_hi(w3.x) + blo.y;
        base[2] = bf_lo(w3.y) + blo.z; base[3] = bf_hi(w3.y) + blo.w;
        base[4] = bf_lo(w3.z) + bhi.x; base[5] = bf_hi(w3.z) + bhi.y;
        base[6] = bf_lo(w3.w) + bhi.z; base[7] = bf_hi(w3.w) + bhi.w;
    }

    float acc[8];
    #pragma unroll
    for (int k = 0; k < 8; ++k) acc[k] = 0.f;

    const unsigned sMax = (unsigned)(n_nodes - 1);
    const unsigned cMax = (unsigned)(NCOMB - 1);

    for (int e = 0; e < cmax; e += 4) {
        // --- batch 1: index loads (independent, clamped in-bounds) ---
        int2 e0 = eb[min(e + 0, cm1)];
        int2 e1 = eb[min(e + 1, cm1)];
        int2 e2 = eb[min(e + 2, cm1)];
        int2 e3 = eb[min(e + 3, cm1)];
        // --- clamp gather targets (garbage-safe for masked slots) ---
        unsigned s0 = min((unsigned)e0.x, sMax), c0 = min((unsigned)e0.y, cMax);
        unsigned s1 = min((unsigned)e1.x, sMax), c1 = min((unsigned)e1.y, cMax);
        unsigned s2 = min((unsigned)e2.x, sMax), c2 = min((unsigned)e2.y, cMax);
        unsigned s3 = min((unsigned)e3.x, sMax), c3 = min((unsigned)e3.y, cMax);
        // --- batch 2: 8 independent 16B gathers ---
        uint4 S0 = *(const uint4*)&xW13bf[(size_t)s0*256 + sub*8];
        uint4 T0 = *(const uint4*)&T2bf  [(size_t)c0*D   + sub*8];
        uint4 S1 = *(const uint4*)&xW13bf[(size_t)s1*256 + sub*8];
        uint4 T1 = *(const uint4*)&T2bf  [(size_t)c1*D   + sub*8];
        uint4 S2 = *(const uint4*)&xW13bf[(size_t)s2*256 + sub*8];
        uint4 T2 = *(const uint4*)&T2bf  [(size_t)c2*D   + sub*8];
        uint4 S3 = *(const uint4*)&xW13bf[(size_t)s3*256 + sub*8];
        uint4 T3 = *(const uint4*)&T2bf  [(size_t)c3*D   + sub*8];
        // --- consume (cndmask-masked; no divergent control flow) ---
        bool m0 = (e + 0) < cnt, m1 = (e + 1) < cnt;
        bool m2 = (e + 2) < cnt, m3 = (e + 3) < cnt;
        #pragma unroll
        for (int w = 0; w < 4; ++w) {
            unsigned Sw0 = (&S0.x)[w], Tw0 = (&T0.x)[w];
            unsigned Sw1 = (&S1.x)[w], Tw1 = (&T1.x)[w];
            unsigned Sw2 = (&S2.x)[w], Tw2 = (&T2.x)[w];
            unsigned Sw3 = (&S3.x)[w], Tw3 = (&T3.x)[w];
            float v0l = lrelu(bf_lo(Sw0) + bf_lo(Tw0) + base[2*w]);
            float v0h = lrelu(bf_hi(Sw0) + bf_hi(Tw0) + base[2*w+1]);
            float v1l = lrelu(bf_lo(Sw1) + bf_lo(Tw1) + base[2*w]);
            float v1h = lrelu(bf_hi(Sw1) + bf_hi(Tw1) + base[2*w+1]);
            float v2l = lrelu(bf_lo(Sw2) + bf_lo(Tw2) + base[2*w]);
            float v2h = lrelu(bf_hi(Sw2) + bf_hi(Tw2) + base[2*w+1]);
            float v3l = lrelu(bf_lo(Sw3) + bf_lo(Tw3) + base[2*w]);
            float v3h = lrelu(bf_hi(Sw3) + bf_hi(Tw3) + base[2*w+1]);
            float a01l = (m0 ? v0l : 0.f) + (m1 ? v1l : 0.f);
            float a23l = (m2 ? v2l : 0.f) + (m3 ? v3l : 0.f);
            float a01h = (m0 ? v0h : 0.f) + (m1 ? v1h : 0.f);
            float a23h = (m2 ? v2h : 0.f) + (m3 ? v3h : 0.f);
            acc[2*w]   += a01l + a23l;
            acc[2*w+1] += a01h + a23h;
        }
    }

    if (!valid) return;
    float inv = 1.f / fmaxf((float)dg, 1.f);
    float4 o0 = make_float4(acc[0]*inv, acc[1]*inv, acc[2]*inv, acc[3]*inv);
    float4 o1 = make_float4(acc[4]*inv, acc[5]*inv, acc[6]*inv, acc[7]*inv);
    *(float4*)&out[(size_t)node*D + sub*8]     = o0;
    *(float4*)&out[(size_t)node*D + sub*8 + 4] = o1;
}

// ---------------------------------------------------------------------------
extern "C" void kernel_launch(void* const* d_in, const int* in_sizes, int n_in,
                              void* d_out, int out_size, void* d_ws, size_t ws_size,
                              hipStream_t stream)
{
    const float* x          = (const float*)d_in[0];
    const float* rel_table  = (const float*)d_in[1];
    const float* time_table = (const float*)d_in[2];
    const float* W_rt       = (const float*)d_in[3];
    const float* b_rt       = (const float*)d_in[4];
    const float* W_fc       = (const float*)d_in[5];
    const float* b_fc       = (const float*)d_in[6];
    const int*   edges      = (const int*)d_in[7];

    int n_nodes = in_sizes[0] / D;   // 50000
    int n_edges = in_sizes[7] / 4;   // 400000
    int nsc     = (n_edges + 255) / 256;   // 1563 scatter blocks (1 e/thr, r5)
    int nxw     = (n_nodes + 63) / 64;     // 782
    int nt2     = (NCOMB + 63) / 64;       // 1312
    int ntot    = nsc + nxw + nt2;         // 3657

    char* ws = (char*)d_ws;
    size_t off = 0;
    auto alloc = [&](size_t bytes) -> void* {
        void* p = ws + off; off += (bytes + 255) & ~(size_t)255; return p;
    };
    unsigned short* xW13bf = (unsigned short*)alloc((size_t)n_nodes * 256 * 2); // 25.6 MB
    unsigned short* T2bf   = (unsigned short*)alloc((size_t)NCOMB * D * 2);     // 21.5 MB
    unsigned short* Wpk13  = (unsigned short*)alloc((size_t)16*4*64*8 * 2);     // 64 KB
    unsigned short* Wpk2   = (unsigned short*)alloc((size_t)8*4*64*8 * 2);      // 32 KB
    float* relP   = (float*)alloc((size_t)NUM_REL * D * sizeof(float));
    float* timP   = (float*)alloc((size_t)NUM_TS * D * sizeof(float));
    int*   deg    = (int*)alloc((size_t)n_nodes * sizeof(int));
    int2*  ebuf   = (int2*)alloc((size_t)n_nodes * MAXDEG * sizeof(int2));      // 25.6 MB
    if (off > ws_size)
        fprintf(stderr, "kernel_launch: workspace too small: need %zu, have %zu\n", off, ws_size);

    hipMemsetAsync(deg, 0, (size_t)n_nodes * sizeof(int), stream);

    k_prep<<<322, 256, 0, stream>>>(rel_table, time_table, W_rt, W_fc,
                                    relP, timP, Wpk13, Wpk2);
    k_mm  <<<ntot, 256, 0, stream>>>(x, Wpk13, xW13bf, n_nodes,
                                     relP, timP, b_rt, Wpk2, T2bf,
                                     edges, n_edges, deg, ebuf,
                                     nsc, nxw, ntot);
    k_agg <<<(n_nodes + 15)/16, 256, 0, stream>>>(deg, ebuf, xW13bf, T2bf,
                                                  b_fc, (float*)d_out, n_nodes);
}

// Round 15
// 164.503 us; speedup vs baseline: 1.2091x; 1.2091x over previous
//
#include <hip/hip_runtime.h>
#include <cstdio>

#define HID 64
#define D 128            // 2*HID
#define NUM_REL 230
#define NUM_TS 365
#define NCOMB (NUM_REL*NUM_TS)   // 83950
#define SLOPE 0.2f
#define XPAD 136         // LDS row stride in bf16 (272 B -> bank stride 4, 2-way = free)
#define MAXDEG 64        // Poisson(8) max degree ~25; P(deg>=64) < 1e-40

typedef __attribute__((ext_vector_type(8))) short short8;
typedef __attribute__((ext_vector_type(4))) float f32x4;

__device__ __forceinline__ float lrelu(float v){ return v >= 0.f ? v : SLOPE*v; }

// bf16 helpers
__device__ __forceinline__ unsigned bf_rne(float f){
    unsigned u = __float_as_uint(f);
    return (u + 0x7fffu + ((u >> 16) & 1u)) >> 16;
}
__device__ __forceinline__ unsigned pk2(float a, float b){
    return bf_rne(a) | (bf_rne(b) << 16);
}
__device__ __forceinline__ float bf_lo(unsigned u){ return __uint_as_float(u << 16); }
__device__ __forceinline__ float bf_hi(unsigned u){ return __uint_as_float(u & 0xffff0000u); }

// ---------------------------------------------------------------------------
// k_prep: parts (relP/timP) + W-pack ONLY.  (round-5 form, ~12 µs)
// ---------------------------------------------------------------------------
__global__ __launch_bounds__(256) void k_prep(
        const float* __restrict__ rel_table, const float* __restrict__ time_table,
        const float* __restrict__ W_rt, const float* __restrict__ W_fc,
        float* __restrict__ relP, float* __restrict__ timP,
        unsigned short* __restrict__ Wpk13, unsigned short* __restrict__ Wpk2)
{
    int b = blockIdx.x;
    if (b < 298) {
        int row = b*2 + (threadIdx.x >> 7);
        int j   = threadIdx.x & 127;
        if (row >= NUM_REL + NUM_TS) return;
        const float* tbl; const float* Wb; float* out;
        if (row < NUM_REL) { tbl = rel_table + row*HID;            Wb = W_rt;          out = relP + row*D; }
        else               { tbl = time_table + (row-NUM_REL)*HID; Wb = W_rt + HID*D;  out = timP + (row-NUM_REL)*D; }
        float acc = 0.f;
        #pragma unroll
        for (int k = 0; k < HID; ++k) acc += tbl[k] * Wb[k*D + j];
        out[j] = acc;
    } else {
        int id = (b - 298)*256 + threadIdx.x;   // 0..6143
        if (id < 4096) {                 // W13 frags
            int mt = id >> 8;            // 0..15
            int s  = (id >> 6) & 3;
            int l  = id & 63;
            int m  = mt*16 + (l & 15);   // output col 0..255
            int kb = s*32 + (l >> 4)*8;
            unsigned short* dst = Wpk13 + ((size_t)(mt*4 + s)*64 + l)*8;
            #pragma unroll
            for (int j = 0; j < 8; ++j) {
                int k = kb + j;
                float v = (m < D) ? W_fc[(size_t)k*D + m]
                                  : W_fc[(size_t)(256 + k)*D + (m - D)];
                dst[j] = (unsigned short)bf_rne(v);
            }
        } else {                         // W2 frags
            int id2 = id - 4096;
            int mt = id2 >> 8;           // 0..7
            int s  = (id2 >> 6) & 3;
            int l  = id2 & 63;
            int m  = mt*16 + (l & 15);
            int kb = s*32 + (l >> 4)*8;
            unsigned short* dst = Wpk2 + ((size_t)(mt*4 + s)*64 + l)*8;
            #pragma unroll
            for (int j = 0; j < 8; ++j) {
                int k = kb + j;
                dst[j] = (unsigned short)bf_rne(W_fc[(size_t)(D + k)*D + m]);
            }
        }
    }
}

// ---------------------------------------------------------------------------
// k_mm — round-12 structure EXACTLY (best measured: 50.3 µs merged, total
// 164.4) with ONE composed change: scatter blocks use 4 edges/thread
// (r6-validated: ~13 µs standalone vs ~30 for 1 e/thr) so the Bresenham
// interleave injects 391 scatter blocks instead of 1563 — fewer block-slots
// stolen from mm, 4x the atomic MLP per scatter wave.
// r14 lesson (barrier-free regression, 78 µs): LDS staging's full-line
// loads ARE the right pattern; barriers stay.
// ---------------------------------------------------------------------------
__device__ __forceinline__ void xw_body(
        int xb, const float* __restrict__ x,
        const unsigned short* __restrict__ Wpk13,
        unsigned short* __restrict__ xW13bf, int n_nodes,
        unsigned short* Xs /* 64*XPAD */, unsigned short* Cs /* 64*XPAD */)
{
    int t = threadIdx.x;
    int nodeBase = xb*64;
    {   // stage X tile (fp32 -> bf16), 4 threads per node row
        int row = t >> 2;
        int k0  = (t & 3)*32;
        int node = nodeBase + row;
        unsigned short* dst = Xs + row*XPAD + k0;
        if (node < n_nodes) {
            const float4* src = (const float4*)(x + (size_t)node*D + k0);
            #pragma unroll
            for (int g = 0; g < 8; ++g) {
                float4 v = src[g];
                *(uint2*)(dst + g*4) = make_uint2(pk2(v.x, v.y), pk2(v.z, v.w));
            }
        } else {
            #pragma unroll
            for (int g = 0; g < 8; ++g)
                *(uint2*)(dst + g*4) = make_uint2(0u, 0u);
        }
    }
    __syncthreads();

    int w = t >> 6, l = t & 63;
    int li = l & 15, q = l >> 4;

    #pragma unroll 1            // halves sequential (acc reuse, reg economy)
    for (int h = 0; h < 2; ++h) {
        f32x4 acc[2][4];
        #pragma unroll
        for (int mi = 0; mi < 2; ++mi)
            #pragma unroll
            for (int ni = 0; ni < 4; ++ni) acc[mi][ni] = (f32x4){0.f,0.f,0.f,0.f};

        #pragma unroll 1
        for (int s = 0; s < 4; ++s) {
            short8 af[2], bf[4];
            #pragma unroll
            for (int mi = 0; mi < 2; ++mi) {
                int mt = w*4 + h*2 + mi;
                af[mi] = *(const short8*)(Wpk13 + ((size_t)(mt*4 + s)*64 + l)*8);
            }
            #pragma unroll
            for (int ni = 0; ni < 4; ++ni)
                bf[ni] = *(const short8*)(Xs + (ni*16 + li)*XPAD + s*32 + q*8);
            #pragma unroll
            for (int mi = 0; mi < 2; ++mi)
                #pragma unroll
                for (int ni = 0; ni < 4; ++ni)
                    acc[mi][ni] = __builtin_amdgcn_mfma_f32_16x16x32_bf16(
                                      af[mi], bf[ni], acc[mi][ni], 0, 0, 0);
        }
        // acc -> Cs (padded stride: 2-way banks, free)
        #pragma unroll
        for (int ni = 0; ni < 4; ++ni)
            #pragma unroll
            for (int mi = 0; mi < 2; ++mi) {
                int node = ni*16 + li;
                int cl   = w*32 + mi*16 + q*4;
                *(uint2*)(Cs + node*XPAD + cl) =
                    make_uint2(pk2(acc[mi][ni][0], acc[mi][ni][1]),
                               pk2(acc[mi][ni][2], acc[mi][ni][3]));
            }
        __syncthreads();
        // coalesced store: per instr, 64 lanes x 16B lane-contiguous = 1KB.
        // global col = (off>>6)*128 + h*64 + (off&63)  (off in bytes)
        #pragma unroll
        for (int k = 0; k < 4; ++k) {
            int flat  = (k*4 + w)*1024 + l*16;
            int nodeL = flat >> 8;
            int off   = flat & 255;
            int node  = nodeBase + nodeL;
            if (node < n_nodes) {
                uint4 v = *(const uint4*)((const char*)Cs + nodeL*(XPAD*2) + off);
                *(uint4*)((char*)(xW13bf + (size_t)node*256)
                          + (off >> 6)*128 + h*64 + (off & 63)) = v;
            }
        }
        __syncthreads();   // Cs reads done before next half rewrites it
    }
}

__device__ __forceinline__ void t2_body(
        int tb, const float* __restrict__ relP, const float* __restrict__ timP,
        const float* __restrict__ b_rt, const unsigned short* __restrict__ Wpk2,
        unsigned short* __restrict__ T2bf,
        unsigned short* Hs /* 64*XPAD */, unsigned short* Cs /* 64*XPAD */)
{
    int t = threadIdx.x;
    int cBase = tb*64;
    {   // stage H tile: lrelu(relP+timP+b) -> bf16, 4 threads per row
        int r  = t >> 2;
        int hk = (t & 3)*32;
        int combo = cBase + r;
        if (combo >= NCOMB) combo = NCOMB - 1;
        int rr = combo / NUM_TS;
        int tt = combo - rr*NUM_TS;
        const float4* rv4 = (const float4*)(relP + (size_t)rr*D + hk);
        const float4* tv4 = (const float4*)(timP + (size_t)tt*D + hk);
        const float4* bv4 = (const float4*)(b_rt + hk);
        unsigned short* dst = Hs + r*XPAD + hk;
        #pragma unroll
        for (int g = 0; g < 8; ++g) {
            float4 rv = rv4[g], tv = tv4[g], bv = bv4[g];
            float v0 = lrelu(rv.x+tv.x+bv.x), v1 = lrelu(rv.y+tv.y+bv.y);
            float v2 = lrelu(rv.z+tv.z+bv.z), v3 = lrelu(rv.w+tv.w+bv.w);
            *(uint2*)(dst + g*4) = make_uint2(pk2(v0,v1), pk2(v2,v3));
        }
    }
    __syncthreads();

    int w = t >> 6, l = t & 63;
    int li = l & 15, q = l >> 4;

    f32x4 acc[2][4];
    #pragma unroll
    for (int mi = 0; mi < 2; ++mi)
        #pragma unroll
        for (int ni = 0; ni < 4; ++ni) acc[mi][ni] = (f32x4){0.f,0.f,0.f,0.f};

    #pragma unroll 1
    for (int s = 0; s < 4; ++s) {
        short8 af[2], bf[4];
        #pragma unroll
        for (int mi = 0; mi < 2; ++mi) {
            int mt = w*2 + mi;
            af[mi] = *(const short8*)(Wpk2 + ((size_t)(mt*4 + s)*64 + l)*8);
        }
        #pragma unroll
        for (int ni = 0; ni < 4; ++ni)
            bf[ni] = *(const short8*)(Hs + (ni*16 + li)*XPAD + s*32 + q*8);
        #pragma unroll
        for (int mi = 0; mi < 2; ++mi)
            #pragma unroll
            for (int ni = 0; ni < 4; ++ni)
                acc[mi][ni] = __builtin_amdgcn_mfma_f32_16x16x32_bf16(
                                  af[mi], bf[ni], acc[mi][ni], 0, 0, 0);
    }
    // acc -> Cs (padded stride: 2-way banks, free)
    #pragma unroll
    for (int ni = 0; ni < 4; ++ni)
        #pragma unroll
        for (int mi = 0; mi < 2; ++mi) {
            int comboL = ni*16 + li;
            int cl     = (w*2 + mi)*16 + q*4;
            *(uint2*)(Cs + comboL*XPAD + cl) =
                make_uint2(pk2(acc[mi][ni][0], acc[mi][ni][1]),
                           pk2(acc[mi][ni][2], acc[mi][ni][3]));
        }
    __syncthreads();
    // coalesced store: T2bf rows are 256B contiguous -> perfect 1KB/instr
    #pragma unroll
    for (int k = 0; k < 4; ++k) {
        int flat = (k*4 + w)*1024 + l*16;
        int cL   = flat >> 8;
        int off  = flat & 255;
        int combo = cBase + cL;
        if (combo < NCOMB) {
            uint4 v = *(const uint4*)((const char*)Cs + cL*(XPAD*2) + off);
            *(uint4*)((char*)(T2bf + (size_t)combo*D) + off) = v;
        }
    }
}

__global__ __launch_bounds__(256, 3) void k_mm(
        const float* __restrict__ x, const unsigned short* __restrict__ Wpk13,
        unsigned short* __restrict__ xW13bf, int n_nodes,
        const float* __restrict__ relP, const float* __restrict__ timP,
        const float* __restrict__ b_rt, const unsigned short* __restrict__ Wpk2,
        unsigned short* __restrict__ T2bf,
        const int* __restrict__ edges, int n_edges,
        int* __restrict__ deg, int2* __restrict__ ebuf,
        int nsc, int nxw, int ntot)
{
    __shared__ __align__(16) unsigned short Hs[64*XPAD];  // 17.4 KB
    __shared__ __align__(16) unsigned short Cs[64*XPAD];  // 17.4 KB
    int b = blockIdx.x;
    // Bresenham interleave: scatter block iff cumulative count increments.
    int cumCur  = (int)(((long long)b       * nsc) / ntot);
    int cumNext = (int)(((long long)(b + 1) * nsc) / ntot);
    if (cumNext > cumCur) {
        // edge bucket-scatter, 4 edges/thread (r6-validated straight-line
        // batching: 64B contiguous read, 4 independent atomics in flight).
        // deg zeroed by hipMemsetAsync blit (round-3 lesson: plain-store
        // zeroing -> stale memory-side atomics).
        int e0 = (cumCur*256 + threadIdx.x)*4;
        const int4* ep = (const int4*)edges;
        if (e0 + 3 < n_edges) {
            int4 a  = ep[e0+0];
            int4 bb = ep[e0+1];
            int4 c  = ep[e0+2];
            int4 d  = ep[e0+3];
            int sa = atomicAdd(&deg[a.y], 1);
            int sb = atomicAdd(&deg[bb.y], 1);
            int sc = atomicAdd(&deg[c.y], 1);
            int sd = atomicAdd(&deg[d.y], 1);
            if (sa < MAXDEG) ebuf[(size_t)a.y*MAXDEG + sa]  = make_int2(a.x,  a.z*NUM_TS + a.w);
            if (sb < MAXDEG) ebuf[(size_t)bb.y*MAXDEG + sb] = make_int2(bb.x, bb.z*NUM_TS + bb.w);
            if (sc < MAXDEG) ebuf[(size_t)c.y*MAXDEG + sc]  = make_int2(c.x,  c.z*NUM_TS + c.w);
            if (sd < MAXDEG) ebuf[(size_t)d.y*MAXDEG + sd]  = make_int2(d.x,  d.z*NUM_TS + d.w);
        } else {
            for (int e = e0; e < n_edges; ++e) {
                int4 ed = ep[e];
                int slot = atomicAdd(&deg[ed.y], 1);
                if (slot < MAXDEG)
                    ebuf[(size_t)ed.y*MAXDEG + slot] = make_int2(ed.x, ed.z*NUM_TS + ed.w);
            }
        }
    } else {
        int cidx = b - cumNext;
        if (cidx < nxw) {
            xw_body(cidx, x, Wpk13, xW13bf, n_nodes, Hs, Cs);
        } else {
            t2_body(cidx - nxw, relP, timP, b_rt, Wpk2, T2bf, Hs, Cs);
        }
    }
}

// ---------------------------------------------------------------------------
// k_agg: 4 nodes per wave, 16 lanes per node, uint4 (16B) gathers.
// (unchanged — at the random-gather floor for this access pattern)
// ---------------------------------------------------------------------------
__global__ __launch_bounds__(256) void k_agg(
        const int* __restrict__ deg, const int2* __restrict__ ebuf,
        const unsigned short* __restrict__ xW13bf,
        const unsigned short* __restrict__ T2bf,
        const float* __restrict__ b_fc,
        float* __restrict__ out, int n_nodes)
{
    int t    = threadIdx.x;
    int lane = t & 63;
    int g    = lane >> 4;             // node group within wave (0..3)
    int sub  = lane & 15;             // lane within group; covers cols sub*8..+7
    int node = blockIdx.x*16 + (t >> 6)*4 + g;
    bool valid = node < n_nodes;
    int nodeC  = valid ? node : n_nodes - 1;

    int dg  = deg[nodeC];
    int cnt = valid ? (dg < MAXDEG ? dg : MAXDEG) : 0;
    int cm1 = cnt > 0 ? cnt - 1 : 0;
    const int2* eb = ebuf + (size_t)nodeC * MAXDEG;

    // wave-max trip count (cnt is uniform within each 16-lane group)
    int cmax = cnt;
    cmax = max(cmax, __shfl_xor(cmax, 16));
    cmax = max(cmax, __shfl_xor(cmax, 32));

    // base = xW3[node] + b_fc for this lane's 8 cols
    float base[8];
    {
        uint4  w3  = *(const uint4*)&xW13bf[(size_t)nodeC*256 + 128 + sub*8];
        float4 blo = *(const float4*)&b_fc[sub*8];
        float4 bhi = *(const float4*)&b_fc[sub*8 + 4];
        base[0] = bf_lo(w3.x) + blo.x; base[1] = bf_hi(w3.x) + blo.y;
        base[2] = bf_lo(w3.y) + blo.z; base[3] = bf_hi(w3.y) + blo.w;
        base[4] = bf_lo(w3.z) + bhi.x; base[5] = bf_hi(w3.z) + bhi.y;
        base[6] = bf_lo(w3.w) + bhi.z; base[7] = bf_hi(w3.w) + bhi.w;
    }

    float acc[8];
    #pragma unroll
    for (int k = 0; k < 8; ++k) acc[k] = 0.f;

    const unsigned sMax = (unsigned)(n_nodes - 1);
    const unsigned cMax = (unsigned)(NCOMB - 1);

    for (int e = 0; e < cmax; e += 4) {
        // --- batch 1: index loads (independent, clamped in-bounds) ---
        int2 e0 = eb[min(e + 0, cm1)];
        int2 e1 = eb[min(e + 1, cm1)];
        int2 e2 = eb[min(e + 2, cm1)];
        int2 e3 = eb[min(e + 3, cm1)];
        // --- clamp gather targets (garbage-safe for masked slots) ---
        unsigned s0 = min((unsigned)e0.x, sMax), c0 = min((unsigned)e0.y, cMax);
        unsigned s1 = min((unsigned)e1.x, sMax), c1 = min((unsigned)e1.y, cMax);
        unsigned s2 = min((unsigned)e2.x, sMax), c2 = min((unsigned)e2.y, cMax);
        unsigned s3 = min((unsigned)e3.x, sMax), c3 = min((unsigned)e3.y, cMax);
        // --- batch 2: 8 independent 16B gathers ---
        uint4 S0 = *(const uint4*)&xW13bf[(size_t)s0*256 + sub*8];
        uint4 T0 = *(const uint4*)&T2bf  [(size_t)c0*D   + sub*8];
        uint4 S1 = *(const uint4*)&xW13bf[(size_t)s1*256 + sub*8];
        uint4 T1 = *(const uint4*)&T2bf  [(size_t)c1*D   + sub*8];
        uint4 S2 = *(const uint4*)&xW13bf[(size_t)s2*256 + sub*8];
        uint4 T2 = *(const uint4*)&T2bf  [(size_t)c2*D   + sub*8];
        uint4 S3 = *(const uint4*)&xW13bf[(size_t)s3*256 + sub*8];
        uint4 T3 = *(const uint4*)&T2bf  [(size_t)c3*D   + sub*8];
        // --- consume (cndmask-masked; no divergent control flow) ---
        bool m0 = (e + 0) < cnt, m1 = (e + 1) < cnt;
        bool m2 = (e + 2) < cnt, m3 = (e + 3) < cnt;
        #pragma unroll
        for (int w = 0; w < 4; ++w) {
            unsigned Sw0 = (&S0.x)[w], Tw0 = (&T0.x)[w];
            unsigned Sw1 = (&S1.x)[w], Tw1 = (&T1.x)[w];
            unsigned Sw2 = (&S2.x)[w], Tw2 = (&T2.x)[w];
            unsigned Sw3 = (&S3.x)[w], Tw3 = (&T3.x)[w];
            float v0l = lrelu(bf_lo(Sw0) + bf_lo(Tw0) + base[2*w]);
            float v0h = lrelu(bf_hi(Sw0) + bf_hi(Tw0) + base[2*w+1]);
            float v1l = lrelu(bf_lo(Sw1) + bf_lo(Tw1) + base[2*w]);
            float v1h = lrelu(bf_hi(Sw1) + bf_hi(Tw1) + base[2*w+1]);
            float v2l = lrelu(bf_lo(Sw2) + bf_lo(Tw2) + base[2*w]);
            float v2h = lrelu(bf_hi(Sw2) + bf_hi(Tw2) + base[2*w+1]);
            float v3l = lrelu(bf_lo(Sw3) + bf_lo(Tw3) + base[2*w]);
            float v3h = lrelu(bf_hi(Sw3) + bf_hi(Tw3) + base[2*w+1]);
            float a01l = (m0 ? v0l : 0.f) + (m1 ? v1l : 0.f);
            float a23l = (m2 ? v2l : 0.f) + (m3 ? v3l : 0.f);
            float a01h = (m0 ? v0h : 0.f) + (m1 ? v1h : 0.f);
            float a23h = (m2 ? v2h : 0.f) + (m3 ? v3h : 0.f);
            acc[2*w]   += a01l + a23l;
            acc[2*w+1] += a01h + a23h;
        }
    }

    if (!valid) return;
    float inv = 1.f / fmaxf((float)dg, 1.f);
    float4 o0 = make_float4(acc[0]*inv, acc[1]*inv, acc[2]*inv, acc[3]*inv);
    float4 o1 = make_float4(acc[4]*inv, acc[5]*inv, acc[6]*inv, acc[7]*inv);
    *(float4*)&out[(size_t)node*D + sub*8]     = o0;
    *(float4*)&out[(size_t)node*D + sub*8 + 4] = o1;
}

// ---------------------------------------------------------------------------
extern "C" void kernel_launch(void* const* d_in, const int* in_sizes, int n_in,
                              void* d_out, int out_size, void* d_ws, size_t ws_size,
                              hipStream_t stream)
{
    const float* x          = (const float*)d_in[0];
    const float* rel_table  = (const float*)d_in[1];
    const float* time_table = (const float*)d_in[2];
    const float* W_rt       = (const float*)d_in[3];
    const float* b_rt       = (const float*)d_in[4];
    const float* W_fc       = (const float*)d_in[5];
    const float* b_fc       = (const float*)d_in[6];
    const int*   edges      = (const int*)d_in[7];

    int n_nodes = in_sizes[0] / D;   // 50000
    int n_edges = in_sizes[7] / 4;   // 400000
    int nsc     = (n_edges/4 + 255) / 256; // 391 scatter blocks (4 e/thr)
    int nxw     = (n_nodes + 63) / 64;     // 782
    int nt2     = (NCOMB + 63) / 64;       // 1312
    int ntot    = nsc + nxw + nt2;         // 2485

    char* ws = (char*)d_ws;
    size_t off = 0;
    auto alloc = [&](size_t bytes) -> void* {
        void* p = ws + off; off += (bytes + 255) & ~(size_t)255; return p;
    };
    unsigned short* xW13bf = (unsigned short*)alloc((size_t)n_nodes * 256 * 2); // 25.6 MB
    unsigned short* T2bf   = (unsigned short*)alloc((size_t)NCOMB * D * 2);     // 21.5 MB
    unsigned short* Wpk13  = (unsigned short*)alloc((size_t)16*4*64*8 * 2);     // 64 KB
    unsigned short* Wpk2   = (unsigned short*)alloc((size_t)8*4*64*8 * 2);      // 32 KB
    float* relP   = (float*)alloc((size_t)NUM_REL * D * sizeof(float));
    float* timP   = (float*)alloc((size_t)NUM_TS * D * sizeof(float));
    int*   deg    = (int*)alloc((size_t)n_nodes * sizeof(int));
    int2*  ebuf   = (int2*)alloc((size_t)n_nodes * MAXDEG * sizeof(int2));      // 25.6 MB
    if (off > ws_size)
        fprintf(stderr, "kernel_launch: workspace too small: need %zu, have %zu\n", off, ws_size);

    hipMemsetAsync(deg, 0, (size_t)n_nodes * sizeof(int), stream);

    k_prep<<<322, 256, 0, stream>>>(rel_table, time_table, W_rt, W_fc,
                                    relP, timP, Wpk13, Wpk2);
    k_mm  <<<ntot, 256, 0, stream>>>(x, Wpk13, xW13bf, n_nodes,
                                     relP, timP, b_rt, Wpk2, T2bf,
                                     edges, n_edges, deg, ebuf,
                                     nsc, nxw, ntot);
    k_agg <<<(n_nodes + 15)/16, 256, 0, stream>>>(deg, ebuf, xW13bf, T2bf,
                                                  b_fc, (float*)d_out, n_nodes);
}

// Round 16
// 163.003 us; speedup vs baseline: 1.2202x; 1.0092x over previous
//
#include <hip/hip_runtime.h>
#include <cstdio>

#define HID 64
#define D 128            // 2*HID
#define NUM_REL 230
#define NUM_TS 365
#define NCOMB (NUM_REL*NUM_TS)   // 83950
#define SLOPE 0.2f
#define XPAD 136         // LDS row stride in bf16 (272 B -> bank stride 4, 2-way = free)
#define MAXDEG 64        // Poisson(8) max degree ~25; P(deg>=64) < 1e-40

typedef __attribute__((ext_vector_type(8))) short short8;
typedef __attribute__((ext_vector_type(4))) float f32x4;

__device__ __forceinline__ float lrelu(float v){ return v >= 0.f ? v : SLOPE*v; }

// bf16 helpers
__device__ __forceinline__ unsigned bf_rne(float f){
    unsigned u = __float_as_uint(f);
    return (u + 0x7fffu + ((u >> 16) & 1u)) >> 16;
}
__device__ __forceinline__ unsigned pk2(float a, float b){
    return bf_rne(a) | (bf_rne(b) << 16);
}
__device__ __forceinline__ float bf_lo(unsigned u){ return __uint_as_float(u << 16); }
__device__ __forceinline__ float bf_hi(unsigned u){ return __uint_as_float(u & 0xffff0000u); }

// ---------------------------------------------------------------------------
// k_prep: parts (relP/timP) + W-pack + ATOMIC deg zeroing (round-16).
// blocks [0,298)        : relP/timP rows (2 rows per block)
// blocks [298,322)      : pack W13^T / W2^T into MFMA A-frag order (bf16)
// blocks [322,322+NZ)   : atomicExch(&deg[i],0)  — replaces the memset
//                         dispatch. r3 showed PLAIN-STORE zeroing + next-
//                         dispatch atomics fails; hypothesis: the zero must
//                         live at the memory-side coherence point the
//                         atomicAdds use. atomicExch puts it there.
// ---------------------------------------------------------------------------
__global__ __launch_bounds__(256) void k_prep(
        const float* __restrict__ rel_table, const float* __restrict__ time_table,
        const float* __restrict__ W_rt, const float* __restrict__ W_fc,
        float* __restrict__ relP, float* __restrict__ timP,
        unsigned short* __restrict__ Wpk13, unsigned short* __restrict__ Wpk2,
        int* __restrict__ deg, int n_nodes)
{
    int b = blockIdx.x;
    if (b < 298) {
        int row = b*2 + (threadIdx.x >> 7);
        int j   = threadIdx.x & 127;
        if (row >= NUM_REL + NUM_TS) return;
        const float* tbl; const float* Wb; float* out;
        if (row < NUM_REL) { tbl = rel_table + row*HID;            Wb = W_rt;          out = relP + row*D; }
        else               { tbl = time_table + (row-NUM_REL)*HID; Wb = W_rt + HID*D;  out = timP + (row-NUM_REL)*D; }
        float acc = 0.f;
        #pragma unroll
        for (int k = 0; k < HID; ++k) acc += tbl[k] * Wb[k*D + j];
        out[j] = acc;
    } else if (b < 322) {
        int id = (b - 298)*256 + threadIdx.x;   // 0..6143
        if (id < 4096) {                 // W13 frags
            int mt = id >> 8;            // 0..15
            int s  = (id >> 6) & 3;
            int l  = id & 63;
            int m  = mt*16 + (l & 15);   // output col 0..255
            int kb = s*32 + (l >> 4)*8;
            unsigned short* dst = Wpk13 + ((size_t)(mt*4 + s)*64 + l)*8;
            #pragma unroll
            for (int j = 0; j < 8; ++j) {
                int k = kb + j;
                float v = (m < D) ? W_fc[(size_t)k*D + m]
                                  : W_fc[(size_t)(256 + k)*D + (m - D)];
                dst[j] = (unsigned short)bf_rne(v);
            }
        } else {                         // W2 frags
            int id2 = id - 4096;
            int mt = id2 >> 8;           // 0..7
            int s  = (id2 >> 6) & 3;
            int l  = id2 & 63;
            int m  = mt*16 + (l & 15);
            int kb = s*32 + (l >> 4)*8;
            unsigned short* dst = Wpk2 + ((size_t)(mt*4 + s)*64 + l)*8;
            #pragma unroll
            for (int j = 0; j < 8; ++j) {
                int k = kb + j;
                dst[j] = (unsigned short)bf_rne(W_fc[(size_t)(D + k)*D + m]);
            }
        }
    } else {
        int i = (b - 322)*256 + threadIdx.x;
        if (i < n_nodes) atomicExch(&deg[i], 0);   // zero at coherence point
    }
}

// ---------------------------------------------------------------------------
// k_mm — round-15 form EXACTLY (best measured: k_mm ~46 µs steady-state):
// Bresenham-interleaved 4-edge/thread scatter + LDS-staged MFMA tiles +
// padded-Cs coalesced epilogue.
// ---------------------------------------------------------------------------
__device__ __forceinline__ void xw_body(
        int xb, const float* __restrict__ x,
        const unsigned short* __restrict__ Wpk13,
        unsigned short* __restrict__ xW13bf, int n_nodes,
        unsigned short* Xs /* 64*XPAD */, unsigned short* Cs /* 64*XPAD */)
{
    int t = threadIdx.x;
    int nodeBase = xb*64;
    {   // stage X tile (fp32 -> bf16), 4 threads per node row
        int row = t >> 2;
        int k0  = (t & 3)*32;
        int node = nodeBase + row;
        unsigned short* dst = Xs + row*XPAD + k0;
        if (node < n_nodes) {
            const float4* src = (const float4*)(x + (size_t)node*D + k0);
            #pragma unroll
            for (int g = 0; g < 8; ++g) {
                float4 v = src[g];
                *(uint2*)(dst + g*4) = make_uint2(pk2(v.x, v.y), pk2(v.z, v.w));
            }
        } else {
            #pragma unroll
            for (int g = 0; g < 8; ++g)
                *(uint2*)(dst + g*4) = make_uint2(0u, 0u);
        }
    }
    __syncthreads();

    int w = t >> 6, l = t & 63;
    int li = l & 15, q = l >> 4;

    #pragma unroll 1            // halves sequential (acc reuse, reg economy)
    for (int h = 0; h < 2; ++h) {
        f32x4 acc[2][4];
        #pragma unroll
        for (int mi = 0; mi < 2; ++mi)
            #pragma unroll
            for (int ni = 0; ni < 4; ++ni) acc[mi][ni] = (f32x4){0.f,0.f,0.f,0.f};

        #pragma unroll 1
        for (int s = 0; s < 4; ++s) {
            short8 af[2], bf[4];
            #pragma unroll
            for (int mi = 0; mi < 2; ++mi) {
                int mt = w*4 + h*2 + mi;
                af[mi] = *(const short8*)(Wpk13 + ((size_t)(mt*4 + s)*64 + l)*8);
            }
            #pragma unroll
            for (int ni = 0; ni < 4; ++ni)
                bf[ni] = *(const short8*)(Xs + (ni*16 + li)*XPAD + s*32 + q*8);
            #pragma unroll
            for (int mi = 0; mi < 2; ++mi)
                #pragma unroll
                for (int ni = 0; ni < 4; ++ni)
                    acc[mi][ni] = __builtin_amdgcn_mfma_f32_16x16x32_bf16(
                                      af[mi], bf[ni], acc[mi][ni], 0, 0, 0);
        }
        // acc -> Cs (padded stride: 2-way banks, free)
        #pragma unroll
        for (int ni = 0; ni < 4; ++ni)
            #pragma unroll
            for (int mi = 0; mi < 2; ++mi) {
                int node = ni*16 + li;
                int cl   = w*32 + mi*16 + q*4;
                *(uint2*)(Cs + node*XPAD + cl) =
                    make_uint2(pk2(acc[mi][ni][0], acc[mi][ni][1]),
                               pk2(acc[mi][ni][2], acc[mi][ni][3]));
            }
        __syncthreads();
        // coalesced store: per instr, 64 lanes x 16B lane-contiguous = 1KB.
        // global col = (off>>6)*128 + h*64 + (off&63)  (off in bytes)
        #pragma unroll
        for (int k = 0; k < 4; ++k) {
            int flat  = (k*4 + w)*1024 + l*16;
            int nodeL = flat >> 8;
            int off   = flat & 255;
            int node  = nodeBase + nodeL;
            if (node < n_nodes) {
                uint4 v = *(const uint4*)((const char*)Cs + nodeL*(XPAD*2) + off);
                *(uint4*)((char*)(xW13bf + (size_t)node*256)
                          + (off >> 6)*128 + h*64 + (off & 63)) = v;
            }
        }
        __syncthreads();   // Cs reads done before next half rewrites it
    }
}

__device__ __forceinline__ void t2_body(
        int tb, const float* __restrict__ relP, const float* __restrict__ timP,
        const float* __restrict__ b_rt, const unsigned short* __restrict__ Wpk2,
        unsigned short* __restrict__ T2bf,
        unsigned short* Hs /* 64*XPAD */, unsigned short* Cs /* 64*XPAD */)
{
    int t = threadIdx.x;
    int cBase = tb*64;
    {   // stage H tile: lrelu(relP+timP+b) -> bf16, 4 threads per row
        int r  = t >> 2;
        int hk = (t & 3)*32;
        int combo = cBase + r;
        if (combo >= NCOMB) combo = NCOMB - 1;
        int rr = combo / NUM_TS;
        int tt = combo - rr*NUM_TS;
        const float4* rv4 = (const float4*)(relP + (size_t)rr*D + hk);
        const float4* tv4 = (const float4*)(timP + (size_t)tt*D + hk);
        const float4* bv4 = (const float4*)(b_rt + hk);
        unsigned short* dst = Hs + r*XPAD + hk;
        #pragma unroll
        for (int g = 0; g < 8; ++g) {
            float4 rv = rv4[g], tv = tv4[g], bv = bv4[g];
            float v0 = lrelu(rv.x+tv.x+bv.x), v1 = lrelu(rv.y+tv.y+bv.y);
            float v2 = lrelu(rv.z+tv.z+bv.z), v3 = lrelu(rv.w+tv.w+bv.w);
            *(uint2*)(dst + g*4) = make_uint2(pk2(v0,v1), pk2(v2,v3));
        }
    }
    __syncthreads();

    int w = t >> 6, l = t & 63;
    int li = l & 15, q = l >> 4;

    f32x4 acc[2][4];
    #pragma unroll
    for (int mi = 0; mi < 2; ++mi)
        #pragma unroll
        for (int ni = 0; ni < 4; ++ni) acc[mi][ni] = (f32x4){0.f,0.f,0.f,0.f};

    #pragma unroll 1
    for (int s = 0; s < 4; ++s) {
        short8 af[2], bf[4];
        #pragma unroll
        for (int mi = 0; mi < 2; ++mi) {
            int mt = w*2 + mi;
            af[mi] = *(const short8*)(Wpk2 + ((size_t)(mt*4 + s)*64 + l)*8);
        }
        #pragma unroll
        for (int ni = 0; ni < 4; ++ni)
            bf[ni] = *(const short8*)(Hs + (ni*16 + li)*XPAD + s*32 + q*8);
        #pragma unroll
        for (int mi = 0; mi < 2; ++mi)
            #pragma unroll
            for (int ni = 0; ni < 4; ++ni)
                acc[mi][ni] = __builtin_amdgcn_mfma_f32_16x16x32_bf16(
                                  af[mi], bf[ni], acc[mi][ni], 0, 0, 0);
    }
    // acc -> Cs (padded stride: 2-way banks, free)
    #pragma unroll
    for (int ni = 0; ni < 4; ++ni)
        #pragma unroll
        for (int mi = 0; mi < 2; ++mi) {
            int comboL = ni*16 + li;
            int cl     = (w*2 + mi)*16 + q*4;
            *(uint2*)(Cs + comboL*XPAD + cl) =
                make_uint2(pk2(acc[mi][ni][0], acc[mi][ni][1]),
                           pk2(acc[mi][ni][2], acc[mi][ni][3]));
        }
    __syncthreads();
    // coalesced store: T2bf rows are 256B contiguous -> perfect 1KB/instr
    #pragma unroll
    for (int k = 0; k < 4; ++k) {
        int flat = (k*4 + w)*1024 + l*16;
        int cL   = flat >> 8;
        int off  = flat & 255;
        int combo = cBase + cL;
        if (combo < NCOMB) {
            uint4 v = *(const uint4*)((const char*)Cs + cL*(XPAD*2) + off);
            *(uint4*)((char*)(T2bf + (size_t)combo*D) + off) = v;
        }
    }
}

__global__ __launch_bounds__(256, 3) void k_mm(
        const float* __restrict__ x, const unsigned short* __restrict__ Wpk13,
        unsigned short* __restrict__ xW13bf, int n_nodes,
        const float* __restrict__ relP, const float* __restrict__ timP,
        const float* __restrict__ b_rt, const unsigned short* __restrict__ Wpk2,
        unsigned short* __restrict__ T2bf,
        const int* __restrict__ edges, int n_edges,
        int* __restrict__ deg, int2* __restrict__ ebuf,
        int nsc, int nxw, int ntot)
{
    __shared__ __align__(16) unsigned short Hs[64*XPAD];  // 17.4 KB
    __shared__ __align__(16) unsigned short Cs[64*XPAD];  // 17.4 KB
    int b = blockIdx.x;
    // Bresenham interleave: scatter block iff cumulative count increments.
    int cumCur  = (int)(((long long)b       * nsc) / ntot);
    int cumNext = (int)(((long long)(b + 1) * nsc) / ntot);
    if (cumNext > cumCur) {
        // edge bucket-scatter, 4 edges/thread (r6-validated straight-line
        // batching). deg zeroed by atomicExch in k_prep (same coherence
        // point as these atomicAdds).
        int e0 = (cumCur*256 + threadIdx.x)*4;
        const int4* ep = (const int4*)edges;
        if (e0 + 3 < n_edges) {
            int4 a  = ep[e0+0];
            int4 bb = ep[e0+1];
            int4 c  = ep[e0+2];
            int4 d  = ep[e0+3];
            int sa = atomicAdd(&deg[a.y], 1);
            int sb = atomicAdd(&deg[bb.y], 1);
            int sc = atomicAdd(&deg[c.y], 1);
            int sd = atomicAdd(&deg[d.y], 1);
            if (sa < MAXDEG) ebuf[(size_t)a.y*MAXDEG + sa]  = make_int2(a.x,  a.z*NUM_TS + a.w);
            if (sb < MAXDEG) ebuf[(size_t)bb.y*MAXDEG + sb] = make_int2(bb.x, bb.z*NUM_TS + bb.w);
            if (sc < MAXDEG) ebuf[(size_t)c.y*MAXDEG + sc]  = make_int2(c.x,  c.z*NUM_TS + c.w);
            if (sd < MAXDEG) ebuf[(size_t)d.y*MAXDEG + sd]  = make_int2(d.x,  d.z*NUM_TS + d.w);
        } else {
            for (int e = e0; e < n_edges; ++e) {
                int4 ed = ep[e];
                int slot = atomicAdd(&deg[ed.y], 1);
                if (slot < MAXDEG)
                    ebuf[(size_t)ed.y*MAXDEG + slot] = make_int2(ed.x, ed.z*NUM_TS + ed.w);
            }
        }
    } else {
        int cidx = b - cumNext;
        if (cidx < nxw) {
            xw_body(cidx, x, Wpk13, xW13bf, n_nodes, Hs, Cs);
        } else {
            t2_body(cidx - nxw, relP, timP, b_rt, Wpk2, T2bf, Hs, Cs);
        }
    }
}

// ---------------------------------------------------------------------------
// k_agg: 4 nodes per wave, 16 lanes per node, uint4 (16B) gathers.
// (unchanged — at the random-gather floor for this access pattern)
// ---------------------------------------------------------------------------
__global__ __launch_bounds__(256) void k_agg(
        const int* __restrict__ deg, const int2* __restrict__ ebuf,
        const unsigned short* __restrict__ xW13bf,
        const unsigned short* __restrict__ T2bf,
        const float* __restrict__ b_fc,
        float* __restrict__ out, int n_nodes)
{
    int t    = threadIdx.x;
    int lane = t & 63;
    int g    = lane >> 4;             // node group within wave (0..3)
    int sub  = lane & 15;             // lane within group; covers cols sub*8..+7
    int node = blockIdx.x*16 + (t >> 6)*4 + g;
    bool valid = node < n_nodes;
    int nodeC  = valid ? node : n_nodes - 1;

    int dg  = deg[nodeC];
    int cnt = valid ? (dg < MAXDEG ? dg : MAXDEG) : 0;
    int cm1 = cnt > 0 ? cnt - 1 : 0;
    const int2* eb = ebuf + (size_t)nodeC * MAXDEG;

    // wave-max trip count (cnt is uniform within each 16-lane group)
    int cmax = cnt;
    cmax = max(cmax, __shfl_xor(cmax, 16));
    cmax = max(cmax, __shfl_xor(cmax, 32));

    // base = xW3[node] + b_fc for this lane's 8 cols
    float base[8];
    {
        uint4  w3  = *(const uint4*)&xW13bf[(size_t)nodeC*256 + 128 + sub*8];
        float4 blo = *(const float4*)&b_fc[sub*8];
        float4 bhi = *(const float4*)&b_fc[sub*8 + 4];
        base[0] = bf_lo(w3.x) + blo.x; base[1] = bf_hi(w3.x) + blo.y;
        base[2] = bf_lo(w3.y) + blo.z; base[3] = bf_hi(w3.y) + blo.w;
        base[4] = bf_lo(w3.z) + bhi.x; base[5] = bf_hi(w3.z) + bhi.y;
        base[6] = bf_lo(w3.w) + bhi.z; base[7] = bf_hi(w3.w) + bhi.w;
    }

    float acc[8];
    #pragma unroll
    for (int k = 0; k < 8; ++k) acc[k] = 0.f;

    const unsigned sMax = (unsigned)(n_nodes - 1);
    const unsigned cMax = (unsigned)(NCOMB - 1);

    for (int e = 0; e < cmax; e += 4) {
        // --- batch 1: index loads (independent, clamped in-bounds) ---
        int2 e0 = eb[min(e + 0, cm1)];
        int2 e1 = eb[min(e + 1, cm1)];
        int2 e2 = eb[min(e + 2, cm1)];
        int2 e3 = eb[min(e + 3, cm1)];
        // --- clamp gather targets (garbage-safe for masked slots) ---
        unsigned s0 = min((unsigned)e0.x, sMax), c0 = min((unsigned)e0.y, cMax);
        unsigned s1 = min((unsigned)e1.x, sMax), c1 = min((unsigned)e1.y, cMax);
        unsigned s2 = min((unsigned)e2.x, sMax), c2 = min((unsigned)e2.y, cMax);
        unsigned s3 = min((unsigned)e3.x, sMax), c3 = min((unsigned)e3.y, cMax);
        // --- batch 2: 8 independent 16B gathers ---
        uint4 S0 = *(const uint4*)&xW13bf[(size_t)s0*256 + sub*8];
        uint4 T0 = *(const uint4*)&T2bf  [(size_t)c0*D   + sub*8];
        uint4 S1 = *(const uint4*)&xW13bf[(size_t)s1*256 + sub*8];
        uint4 T1 = *(const uint4*)&T2bf  [(size_t)c1*D   + sub*8];
        uint4 S2 = *(const uint4*)&xW13bf[(size_t)s2*256 + sub*8];
        uint4 T2 = *(const uint4*)&T2bf  [(size_t)c2*D   + sub*8];
        uint4 S3 = *(const uint4*)&xW13bf[(size_t)s3*256 + sub*8];
        uint4 T3 = *(const uint4*)&T2bf  [(size_t)c3*D   + sub*8];
        // --- consume (cndmask-masked; no divergent control flow) ---
        bool m0 = (e + 0) < cnt, m1 = (e + 1) < cnt;
        bool m2 = (e + 2) < cnt, m3 = (e + 3) < cnt;
        #pragma unroll
        for (int w = 0; w < 4; ++w) {
            unsigned Sw0 = (&S0.x)[w], Tw0 = (&T0.x)[w];
            unsigned Sw1 = (&S1.x)[w], Tw1 = (&T1.x)[w];
            unsigned Sw2 = (&S2.x)[w], Tw2 = (&T2.x)[w];
            unsigned Sw3 = (&S3.x)[w], Tw3 = (&T3.x)[w];
            float v0l = lrelu(bf_lo(Sw0) + bf_lo(Tw0) + base[2*w]);
            float v0h = lrelu(bf_hi(Sw0) + bf_hi(Tw0) + base[2*w+1]);
            float v1l = lrelu(bf_lo(Sw1) + bf_lo(Tw1) + base[2*w]);
            float v1h = lrelu(bf_hi(Sw1) + bf_hi(Tw1) + base[2*w+1]);
            float v2l = lrelu(bf_lo(Sw2) + bf_lo(Tw2) + base[2*w]);
            float v2h = lrelu(bf_hi(Sw2) + bf_hi(Tw2) + base[2*w+1]);
            float v3l = lrelu(bf_lo(Sw3) + bf_lo(Tw3) + base[2*w]);
            float v3h = lrelu(bf_hi(Sw3) + bf_hi(Tw3) + base[2*w+1]);
            float a01l = (m0 ? v0l : 0.f) + (m1 ? v1l : 0.f);
            float a23l = (m2 ? v2l : 0.f) + (m3 ? v3l : 0.f);
            float a01h = (m0 ? v0h : 0.f) + (m1 ? v1h : 0.f);
            float a23h = (m2 ? v2h : 0.f) + (m3 ? v3h : 0.f);
            acc[2*w]   += a01l + a23l;
            acc[2*w+1] += a01h + a23h;
        }
    }

    if (!valid) return;
    float inv = 1.f / fmaxf((float)dg, 1.f);
    float4 o0 = make_float4(acc[0]*inv, acc[1]*inv, acc[2]*inv, acc[3]*inv);
    float4 o1 = make_float4(acc[4]*inv, acc[5]*inv, acc[6]*inv, acc[7]*inv);
    *(float4*)&out[(size_t)node*D + sub*8]     = o0;
    *(float4*)&out[(size_t)node*D + sub*8 + 4] = o1;
}

// ---------------------------------------------------------------------------
extern "C" void kernel_launch(void* const* d_in, const int* in_sizes, int n_in,
                              void* d_out, int out_size, void* d_ws, size_t ws_size,
                              hipStream_t stream)
{
    const float* x          = (const float*)d_in[0];
    const float* rel_table  = (const float*)d_in[1];
    const float* time_table = (const float*)d_in[2];
    const float* W_rt       = (const float*)d_in[3];
    const float* b_rt       = (const float*)d_in[4];
    const float* W_fc       = (const float*)d_in[5];
    const float* b_fc       = (const float*)d_in[6];
    const int*   edges      = (const int*)d_in[7];

    int n_nodes = in_sizes[0] / D;   // 50000
    int n_edges = in_sizes[7] / 4;   // 400000
    int nblkZ   = (n_nodes + 255) / 256;   // 196 atomic-zero blocks
    int nsc     = (n_edges/4 + 255) / 256; // 391 scatter blocks (4 e/thr)
    int nxw     = (n_nodes + 63) / 64;     // 782
    int nt2     = (NCOMB + 63) / 64;       // 1312
    int ntot    = nsc + nxw + nt2;         // 2485

    char* ws = (char*)d_ws;
    size_t off = 0;
    auto alloc = [&](size_t bytes) -> void* {
        void* p = ws + off; off += (bytes + 255) & ~(size_t)255; return p;
    };
    unsigned short* xW13bf = (unsigned short*)alloc((size_t)n_nodes * 256 * 2); // 25.6 MB
    unsigned short* T2bf   = (unsigned short*)alloc((size_t)NCOMB * D * 2);     // 21.5 MB
    unsigned short* Wpk13  = (unsigned short*)alloc((size_t)16*4*64*8 * 2);     // 64 KB
    unsigned short* Wpk2   = (unsigned short*)alloc((size_t)8*4*64*8 * 2);      // 32 KB
    float* relP   = (float*)alloc((size_t)NUM_REL * D * sizeof(float));
    float* timP   = (float*)alloc((size_t)NUM_TS * D * sizeof(float));
    int*   deg    = (int*)alloc((size_t)n_nodes * sizeof(int));
    int2*  ebuf   = (int2*)alloc((size_t)n_nodes * MAXDEG * sizeof(int2));      // 25.6 MB
    if (off > ws_size)
        fprintf(stderr, "kernel_launch: workspace too small: need %zu, have %zu\n", off, ws_size);

    k_prep<<<322 + nblkZ, 256, 0, stream>>>(rel_table, time_table, W_rt, W_fc,
                                            relP, timP, Wpk13, Wpk2,
                                            deg, n_nodes);
    k_mm  <<<ntot, 256, 0, stream>>>(x, Wpk13, xW13bf, n_nodes,
                                     relP, timP, b_rt, Wpk2, T2bf,
                                     edges, n_edges, deg, ebuf,
                                     nsc, nxw, ntot);
    k_agg <<<(n_nodes + 15)/16, 256, 0, stream>>>(deg, ebuf, xW13bf, T2bf,
                                                  b_fc, (float*)d_out, n_nodes);
}